// Round 12
// baseline (475.825 us; speedup 1.0000x reference)
//
#include <hip/hip_runtime.h>

#define Nn   50000
#define Ee   800000
#define INC  256
#define HIDd 128
#define RR   8
#define BB   4
#define LL   3
#define RN   (RR * Nn)   // 400000
#define NC2  49          // ceil(Nn / 1024)

typedef _Float16 f16;
typedef _Float16 f16x4 __attribute__((ext_vector_type(4)));
typedef _Float16 f16x8 __attribute__((ext_vector_type(8)));
typedef float    f32x4 __attribute__((ext_vector_type(4)));

static inline size_t align256(size_t x) { return (x + 255) & ~(size_t)255; }

// ---------------- edge counting: per-(r,d) for invc, per-d for CSR ----------------

__global__ void count_k(const int* __restrict__ ei, const int* __restrict__ et,
                        int* __restrict__ cnt, int* __restrict__ cntd) {
    int e = blockIdx.x * 256 + threadIdx.x;
    if (e < Ee) {
        int d = ei[Ee + e];
        int r = et[e];
        atomicAdd(&cnt[r * Nn + d], 1);
        atomicAdd(&cntd[d], 1);
    }
}

// invc2[d][r] = 1/max(cnt[r][d],1)  — thread per d, coalesced reads and writes
__global__ __launch_bounds__(256) void invc2_k(const int* __restrict__ cnt,
                                               float* __restrict__ invc2) {
    int d = blockIdx.x * 256 + threadIdx.x;
    if (d < Nn) {
        float iv[8];
#pragma unroll
        for (int r = 0; r < 8; ++r) {
            int c = cnt[r * Nn + d];
            iv[r] = 1.0f / (float)(c > 1 ? c : 1);
        }
        *(float4*)(invc2 + (size_t)d * 8)     = *(float4*)&iv[0];
        *(float4*)(invc2 + (size_t)d * 8 + 4) = *(float4*)&iv[4];
    }
}

// ------- parallel exclusive scan over cntd[Nn] -> off2/cursor2 -------

__global__ __launch_bounds__(256) void chunksum2_k(const int* __restrict__ cntd,
                                                   int* __restrict__ csum2) {
    int c = blockIdx.x;
    int t = threadIdx.x;
    int idx4 = c * 256 + t;            // int4 index; Nn/4 = 12500
    int s = 0;
    if (idx4 < Nn / 4) {
        int4 v = ((const int4*)cntd)[idx4];
        s = v.x + v.y + v.z + v.w;
    }
#pragma unroll
    for (int o = 1; o < 64; o <<= 1) s += __shfl_xor(s, o);
    __shared__ int ws[4];
    if ((t & 63) == 0) ws[t >> 6] = s;
    __syncthreads();
    if (t == 0) csum2[c] = ws[0] + ws[1] + ws[2] + ws[3];
}

__global__ __launch_bounds__(64) void chunkscan2_k(const int* __restrict__ csum2,
                                                   int* __restrict__ cbase2,
                                                   int* __restrict__ off2) {
    int t = threadIdx.x;
    int v = (t < NC2) ? csum2[t] : 0;
    int incl = v;
#pragma unroll
    for (int o = 1; o < 64; o <<= 1) {
        int u = __shfl_up(incl, o);
        if (t >= o) incl += u;
    }
    if (t < NC2) cbase2[t] = incl - v;
    if (t == 63) off2[Nn] = incl;   // == Ee
}

__global__ __launch_bounds__(256) void writeoff2_k(const int* __restrict__ cntd,
                                                   const int* __restrict__ cbase2,
                                                   int* __restrict__ off2,
                                                   int* __restrict__ cursor2) {
    int c = blockIdx.x;
    int t = threadIdx.x;
    int idx4 = c * 256 + t;
    bool ok = idx4 < Nn / 4;
    int4 v = make_int4(0, 0, 0, 0);
    if (ok) v = ((const int4*)cntd)[idx4];
    int s = v.x + v.y + v.z + v.w;
    int lane = t & 63;
    int incl = s;
#pragma unroll
    for (int o = 1; o < 64; o <<= 1) {
        int u = __shfl_up(incl, o);
        if (lane >= o) incl += u;
    }
    __shared__ int wsum[4];
    if (lane == 63) wsum[t >> 6] = incl;
    __syncthreads();
    int w = t >> 6;
    int wpre = 0;
    if (w > 0) wpre += wsum[0];
    if (w > 1) wpre += wsum[1];
    if (w > 2) wpre += wsum[2];
    int excl = cbase2[c] + wpre + incl - s;
    if (ok) {
        int o0 = excl;
        int o1 = o0 + v.x;
        int o2 = o1 + v.y;
        int o3 = o2 + v.z;
        int4 ov = make_int4(o0, o1, o2, o3);
        ((int4*)off2)[idx4] = ov;
        ((int4*)cursor2)[idx4] = ov;
    }
}

// scatter: es2[p] = src | (r<<16)   (src < 50000 < 2^16)
__global__ void scatter2_k(const int* __restrict__ ei, const int* __restrict__ et,
                           int* __restrict__ cursor2, int* __restrict__ es2) {
    int e = blockIdx.x * 256 + threadIdx.x;
    if (e < Ee) {
        int s = ei[e];
        int d = ei[Ee + e];
        int r = et[e];
        int p = atomicAdd(&cursor2[d], 1);
        es2[p] = s | (r << 16);
    }
}

// ------- W^T (fp16): chunk 0 = root^T, chunks 1..4 = bases_b^T, per layer -------

__global__ void makewT_k(const float* __restrict__ bases, const float* __restrict__ root,
                         f16* __restrict__ WT) {
    int idx = blockIdx.x * 256 + threadIdx.x;   // < L*5*16384
    int l = idx / (5 * 16384);
    int rem = idx % (5 * 16384);
    int c = rem >> 14;
    int n = (rem >> 7) & 127;
    int k = rem & 127;
    float v = (c == 0) ? root[l * 16384 + k * 128 + n]
                       : bases[((l * BB + (c - 1)) << 14) + k * 128 + n];
    WT[idx] = (f16)v;
}

// ------- w1 (256x128 fp32) -> w1hT (128n x 256k fp16) -------

__global__ void makew1T_k(const float* __restrict__ w1, f16* __restrict__ w1hT) {
    int idx = blockIdx.x * 256 + threadIdx.x;   // < 32768
    int n = idx >> 8, k = idx & 255;
    w1hT[idx] = (f16)w1[k * 128 + n];
}

// ---------------- lin1 via MFMA: relu(x @ w1hT^T + b1)*temp0 -> curh(f16);
//                  out = b2 + temp0 * (cur @ W2) ----------------

__global__ __launch_bounds__(256, 2) void lin1m_k(const float* __restrict__ x,
                                                  const f16* __restrict__ w1hT,
                                                  const float* __restrict__ b1,
                                                  const float* __restrict__ temp,
                                                  const float* __restrict__ w2,
                                                  const float* __restrict__ b2,
                                                  f16* __restrict__ curh,
                                                  float* __restrict__ out) {
    __shared__ f16 Ah[128 * 136];
    __shared__ f16 Bh[128 * 136];
    __shared__ float ws2[256];
    __shared__ float bsh[2];
    int t = threadIdx.x;
    int v0 = blockIdx.x * 128;
    int w = t >> 6, lane = t & 63;
    int wr = w >> 1, wc = w & 1;
    int l15 = lane & 15, l4 = lane >> 4;
    int srow = t >> 1, sseg = t & 1;

    ws2[t] = w2[t];
    if (t < 2) bsh[t] = b2[t];

    f32x4 acc[4][4] = {};

    for (int c = 0; c < 2; ++c) {
        __syncthreads();
        {
            f16* dst = Ah + srow * 136 + sseg * 64;
            if (v0 + srow < Nn) {
                const float* src = x + (size_t)(v0 + srow) * INC + c * 128 + sseg * 64;
#pragma unroll
                for (int j = 0; j < 16; ++j) {
                    float4 f = *(const float4*)(src + j * 4);
                    f16x4 o;
                    o[0] = (f16)f.x; o[1] = (f16)f.y; o[2] = (f16)f.z; o[3] = (f16)f.w;
                    *(f16x4*)(dst + j * 4) = o;
                }
            } else {
                f16x8 z = {};
#pragma unroll
                for (int j = 0; j < 8; ++j)
                    *(f16x8*)(dst + j * 8) = z;
            }
        }
        {
            const f16* src = w1hT + srow * 256 + c * 128 + sseg * 64;
            f16* dst = Bh + srow * 136 + sseg * 64;
#pragma unroll
            for (int j = 0; j < 8; ++j)
                *(f16x8*)(dst + j * 8) = *(const f16x8*)(src + j * 8);
        }
        __syncthreads();
#pragma unroll
        for (int ks = 0; ks < 4; ++ks) {
            f16x8 af[4], bf[4];
#pragma unroll
            for (int mf = 0; mf < 4; ++mf)
                af[mf] = *(const f16x8*)(Ah + (wr * 64 + mf * 16 + l15) * 136 + ks * 32 + l4 * 8);
#pragma unroll
            for (int nf = 0; nf < 4; ++nf)
                bf[nf] = *(const f16x8*)(Bh + (wc * 64 + nf * 16 + l15) * 136 + ks * 32 + l4 * 8);
#pragma unroll
            for (int mf = 0; mf < 4; ++mf)
#pragma unroll
                for (int nf = 0; nf < 4; ++nf)
                    acc[mf][nf] = __builtin_amdgcn_mfma_f32_16x16x32_f16(af[mf], bf[nf], acc[mf][nf], 0, 0, 0);
        }
    }

    __syncthreads();
    float t0 = temp[0];
    float bs[4];
#pragma unroll
    for (int nf = 0; nf < 4; ++nf) bs[nf] = b1[wc * 64 + nf * 16 + l15];
#pragma unroll
    for (int mf = 0; mf < 4; ++mf)
#pragma unroll
        for (int nf = 0; nf < 4; ++nf)
#pragma unroll
            for (int j = 0; j < 4; ++j) {
                float val = fmaxf(acc[mf][nf][j] + bs[nf], 0.f) * t0;
                Ah[(wr * 64 + mf * 16 + l4 * 4 + j) * 136 + wc * 64 + nf * 16 + l15] = (f16)val;
            }
    __syncthreads();
    if (v0 + srow < Nn) {
        size_t gb = (size_t)(v0 + srow) * HIDd + sseg * 64;
        const f16* cr = Ah + srow * 136 + sseg * 64;
#pragma unroll
        for (int j = 0; j < 8; ++j)
            *(f16x8*)(curh + gb + j * 8) = *(const f16x8*)(cr + j * 8);
        float d0 = 0.f, d1 = 0.f;
#pragma unroll
        for (int q = 0; q < 8; ++q) {
            f16x8 cv = *(const f16x8*)(cr + q * 8);
            const float* wp = &ws2[sseg * 128 + q * 16];
#pragma unroll
            for (int j = 0; j < 8; ++j) {
                float c = (float)cv[j];
                d0 += c * wp[j * 2];
                d1 += c * wp[j * 2 + 1];
            }
        }
        d0 += __shfl_xor(d0, 1);
        d1 += __shfl_xor(d1, 1);
        if (sseg == 0) {
            out[(v0 + srow) * 2 + 0] = bsh[0] + d0;
            out[(v0 + srow) * 2 + 1] = bsh[1] + d1;
        }
    } else {
        float d0 = 0.f, d1 = 0.f;
        d0 += __shfl_xor(d0, 1);
        d1 += __shfl_xor(d1, 1);
    }
}

// ------- basis aggregation over dst-CSR: 16-lane group per dst (16 dst/block);
//         per-edge fold of comp[r,b]*invc[r,d] into 4 basis accumulators -------

__global__ __launch_bounds__(256) void meanr2_k(const f16* __restrict__ curh,
                                                const int* __restrict__ es2,
                                                const int* __restrict__ off2,
                                                const float* __restrict__ invc2,
                                                const float* __restrict__ comp_l,
                                                f16* __restrict__ aggb) {
    __shared__ float wls[16][8][4];
    int t = threadIdx.x;
    int g = t >> 4;
    int lane = t & 15;
    int d = blockIdx.x * 16 + g;
    for (int f = t; f < 512; f += 256) {
        int g2 = f >> 5, rb = f & 31, r = rb >> 2;
        int dd = blockIdx.x * 16 + g2;
        wls[g2][r][rb & 3] = comp_l[rb] * invc2[(size_t)dd * 8 + r];
    }
    __syncthreads();
    int e = off2[d], e1 = off2[d + 1];
    float acc0[8] = {}, acc1[8] = {}, acc2[8] = {}, acc3[8] = {};
    const f16* cb = curh + lane * 8;
    for (; e + 2 <= e1; e += 2) {
        int v0 = es2[e], v1 = es2[e + 1];
        f16x8 row0 = *(const f16x8*)(cb + (size_t)(v0 & 0xFFFF) * HIDd);
        f16x8 row1 = *(const f16x8*)(cb + (size_t)(v1 & 0xFFFF) * HIDd);
        float4 w0 = *(float4*)&wls[g][v0 >> 16][0];
        float4 w1 = *(float4*)&wls[g][v1 >> 16][0];
#pragma unroll
        for (int j = 0; j < 8; ++j) {
            float a = (float)row0[j], b = (float)row1[j];
            acc0[j] += w0.x * a + w1.x * b;
            acc1[j] += w0.y * a + w1.y * b;
            acc2[j] += w0.z * a + w1.z * b;
            acc3[j] += w0.w * a + w1.w * b;
        }
    }
    if (e < e1) {
        int v0 = es2[e];
        f16x8 row0 = *(const f16x8*)(cb + (size_t)(v0 & 0xFFFF) * HIDd);
        float4 w0 = *(float4*)&wls[g][v0 >> 16][0];
#pragma unroll
        for (int j = 0; j < 8; ++j) {
            float a = (float)row0[j];
            acc0[j] += w0.x * a;
            acc1[j] += w0.y * a;
            acc2[j] += w0.z * a;
            acc3[j] += w0.w * a;
        }
    }
    f16* op = aggb + (size_t)d * 512 + lane * 8;
    f16x8 o0, o1, o2, o3;
#pragma unroll
    for (int j = 0; j < 8; ++j) {
        o0[j] = (f16)acc0[j];
        o1[j] = (f16)acc1[j];
        o2[j] = (f16)acc2[j];
        o3[j] = (f16)acc3[j];
    }
    *(f16x8*)(op)       = o0;
    *(f16x8*)(op + 128) = o1;
    *(f16x8*)(op + 256) = o2;
    *(f16x8*)(op + 384) = o3;
}

// ------- dense fp16 MFMA GEMM: C = [curh | aggb0..3] (K=640) @ WT^T, in-place curh;
//         out += temp[tidx] * (cur @ W2) -------

__global__ __launch_bounds__(256, 2) void gemm_k(const f16* __restrict__ curh,
                                                 const f16* __restrict__ aggb,
                                                 const f16* __restrict__ WTl,
                                                 const float* __restrict__ bias,
                                                 const float* __restrict__ temp, int tidx,
                                                 const float* __restrict__ w2,
                                                 f16* __restrict__ curh_next,
                                                 float* __restrict__ out,
                                                 int dorelu) {
    __shared__ f16 Ah[128 * 136];
    __shared__ f16 Bh[128 * 136];
    __shared__ float ws2[256];
    int t = threadIdx.x;
    int v0 = blockIdx.x * 128;
    int w = t >> 6, lane = t & 63;
    int wr = w >> 1, wc = w & 1;
    int l15 = lane & 15, l4 = lane >> 4;
    int srow = t >> 1, sseg = t & 1;

    ws2[t] = w2[t];

    f32x4 acc[4][4] = {};

    for (int c = 0; c < 5; ++c) {
        __syncthreads();
        {
            f16* dst = Ah + srow * 136 + sseg * 64;
            if (v0 + srow < Nn) {
                const f16* src = (c == 0)
                    ? curh + (size_t)(v0 + srow) * HIDd + sseg * 64
                    : aggb + ((size_t)(v0 + srow) * 4 + (c - 1)) * HIDd + sseg * 64;
#pragma unroll
                for (int j = 0; j < 8; ++j)
                    *(f16x8*)(dst + j * 8) = *(const f16x8*)(src + j * 8);
            } else {
                f16x8 z = {};
#pragma unroll
                for (int j = 0; j < 8; ++j)
                    *(f16x8*)(dst + j * 8) = z;
            }
        }
        {
            const f16* src = WTl + (c << 14) + srow * HIDd + sseg * 64;
            f16* dst = Bh + srow * 136 + sseg * 64;
#pragma unroll
            for (int j = 0; j < 8; ++j)
                *(f16x8*)(dst + j * 8) = *(const f16x8*)(src + j * 8);
        }
        __syncthreads();
#pragma unroll
        for (int ks = 0; ks < 4; ++ks) {
            f16x8 af[4], bf[4];
#pragma unroll
            for (int mf = 0; mf < 4; ++mf)
                af[mf] = *(const f16x8*)(Ah + (wr * 64 + mf * 16 + l15) * 136 + ks * 32 + l4 * 8);
#pragma unroll
            for (int nf = 0; nf < 4; ++nf)
                bf[nf] = *(const f16x8*)(Bh + (wc * 64 + nf * 16 + l15) * 136 + ks * 32 + l4 * 8);
#pragma unroll
            for (int mf = 0; mf < 4; ++mf)
#pragma unroll
                for (int nf = 0; nf < 4; ++nf)
                    acc[mf][nf] = __builtin_amdgcn_mfma_f32_16x16x32_f16(af[mf], bf[nf], acc[mf][nf], 0, 0, 0);
        }
    }

    __syncthreads();
    float tl = temp[tidx];
    float bs[4];
#pragma unroll
    for (int nf = 0; nf < 4; ++nf) bs[nf] = bias[wc * 64 + nf * 16 + l15];
#pragma unroll
    for (int mf = 0; mf < 4; ++mf)
#pragma unroll
        for (int nf = 0; nf < 4; ++nf)
#pragma unroll
            for (int j = 0; j < 4; ++j) {
                float val = acc[mf][nf][j] + bs[nf];
                if (dorelu) val = fmaxf(val, 0.f);
                Ah[(wr * 64 + mf * 16 + l4 * 4 + j) * 136 + wc * 64 + nf * 16 + l15] = (f16)val;
            }
    __syncthreads();
    if (v0 + srow < Nn) {
        size_t gb = (size_t)(v0 + srow) * HIDd + sseg * 64;
        const f16* cr = Ah + srow * 136 + sseg * 64;
#pragma unroll
        for (int j = 0; j < 8; ++j)
            *(f16x8*)(curh_next + gb + j * 8) = *(const f16x8*)(cr + j * 8);
        float d0 = 0.f, d1 = 0.f;
#pragma unroll
        for (int q = 0; q < 8; ++q) {
            f16x8 cv = *(const f16x8*)(cr + q * 8);
            const float* wp = &ws2[sseg * 128 + q * 16];
#pragma unroll
            for (int j = 0; j < 8; ++j) {
                float c = (float)cv[j];
                d0 += c * wp[j * 2];
                d1 += c * wp[j * 2 + 1];
            }
        }
        d0 += __shfl_xor(d0, 1);
        d1 += __shfl_xor(d1, 1);
        if (sseg == 0) {
            out[(v0 + srow) * 2 + 0] += tl * d0;
            out[(v0 + srow) * 2 + 1] += tl * d1;
        }
    } else {
        float d0 = 0.f, d1 = 0.f;
        d0 += __shfl_xor(d0, 1);
        d1 += __shfl_xor(d1, 1);
    }
}

// ---------------- host ----------------

extern "C" void kernel_launch(void* const* d_in, const int* in_sizes, int n_in,
                              void* d_out, int out_size, void* d_ws, size_t ws_size,
                              hipStream_t stream) {
    (void)in_sizes; (void)n_in; (void)out_size; (void)ws_size;
    const float* x        = (const float*)d_in[0];
    const int*   ei       = (const int*)d_in[1];
    const int*   et       = (const int*)d_in[2];
    const float* lin1_w   = (const float*)d_in[3];
    const float* lin1_b   = (const float*)d_in[4];
    const float* bases    = (const float*)d_in[5];
    const float* comp     = (const float*)d_in[6];
    const float* root     = (const float*)d_in[7];
    const float* bias_cv  = (const float*)d_in[8];
    const float* lin2_w   = (const float*)d_in[9];
    const float* lin2_b   = (const float*)d_in[10];
    const float* temp     = (const float*)d_in[11];
    float* out = (float*)d_out;

    char* w = (char*)d_ws;
    int*   off2    = (int*)w;    w += align256((size_t)(Nn + 1) * 4);
    int*   cnt     = (int*)w;    w += align256((size_t)RN * 4);
    int*   cntd    = (int*)w;    w += align256((size_t)Nn * 4);
    int*   cursor2 = (int*)w;    w += align256((size_t)Nn * 4);
    float* invc2   = (float*)w;  w += align256((size_t)RN * 4);
    int*   csum2   = (int*)w;    w += align256((size_t)NC2 * 4);
    int*   cbase2  = (int*)w;    w += align256((size_t)NC2 * 4);
    int*   es2     = (int*)w;    w += align256((size_t)Ee * 4);
    f16*   WT      = (f16*)w;    w += align256((size_t)LL * 5 * HIDd * HIDd * 2);
    f16*   w1hT    = (f16*)w;    w += align256((size_t)HIDd * INC * 2);
    f16*   curh    = (f16*)w;    w += align256((size_t)Nn * HIDd * 2);
    f16*   aggb    = (f16*)w;    w += align256((size_t)Nn * 4 * HIDd * 2);

    hipMemsetAsync(cnt, 0, (size_t)RN * 4, stream);
    hipMemsetAsync(cntd, 0, (size_t)Nn * 4, stream);
    count_k<<<(Ee + 255) / 256, 256, 0, stream>>>(ei, et, cnt, cntd);
    invc2_k<<<(Nn + 255) / 256, 256, 0, stream>>>(cnt, invc2);
    chunksum2_k<<<NC2, 256, 0, stream>>>(cntd, csum2);
    chunkscan2_k<<<1, 64, 0, stream>>>(csum2, cbase2, off2);
    writeoff2_k<<<NC2, 256, 0, stream>>>(cntd, cbase2, off2, cursor2);
    scatter2_k<<<(Ee + 255) / 256, 256, 0, stream>>>(ei, et, cursor2, es2);
    makewT_k<<<(LL * 5 * 16384) / 256, 256, 0, stream>>>(bases, root, WT);
    makew1T_k<<<(HIDd * INC) / 256, 256, 0, stream>>>(lin1_w, w1hT);
    lin1m_k<<<(Nn + 127) / 128, 256, 0, stream>>>(x, w1hT, lin1_b, temp, lin2_w, lin2_b,
                                                  curh, out);

    for (int l = 0; l < LL; ++l) {
        meanr2_k<<<Nn / 16, 256, 0, stream>>>(curh, es2, off2, invc2,
                                              comp + l * RR * BB, aggb);
        gemm_k<<<(Nn + 127) / 128, 256, 0, stream>>>(
            curh, aggb, WT + (size_t)l * 5 * 16384, bias_cv + l * HIDd,
            temp, l + 1, lin2_w, curh, out, (l < LL - 1) ? 1 : 0);
    }
}